// Round 2
// baseline (584.010 us; speedup 1.0000x reference)
//
#include <hip/hip_runtime.h>
#include <math.h>

// Problem constants
#define B_   128
#define N_   1369
#define DINO_ 384
#define CLIP_ 512
#define H_   8
#define D_   64
#define CHUNKS 4
#define CHUNK_SZ 343   // ceil(1369/4); last chunk = 340

// ---------------------------------------------------------------------------
// Kernel AB: per batch b, compute Q = clip@Wq + bq (512), then the folded
// key vector qk[b,h,:] = (1/(8*temp)) * Wk[:, h*64:(h+1)*64] @ Q[b, h*64:...]
// grid = 128 blocks, 256 threads.
// ---------------------------------------------------------------------------
__global__ __launch_bounds__(256) void kab(const float* __restrict__ clip,
                                           const float* __restrict__ Wq,
                                           const float* __restrict__ bq,
                                           const float* __restrict__ Wk,
                                           const float* __restrict__ temp,
                                           float* __restrict__ qk) {
  const int b = blockIdx.x;
  const int tid = threadIdx.x;
  __shared__ float cl[CLIP_];
  __shared__ float q2[CLIP_];
  cl[tid] = clip[b * CLIP_ + tid];
  cl[tid + 256] = clip[b * CLIP_ + tid + 256];
  __syncthreads();
  const float rs = 1.0f / (8.0f * temp[0]);   // scale = sqrt(D)*temperature
  // Q2: each thread computes 2 output columns
  #pragma unroll
  for (int rep = 0; rep < 2; ++rep) {
    const int c = tid + rep * 256;
    float acc = bq[c];
    #pragma unroll 8
    for (int j = 0; j < CLIP_; ++j) acc += cl[j] * Wq[j * CLIP_ + c];
    q2[c] = acc;
  }
  __syncthreads();
  // qk[h][j] = rs * sum_d Wk[j*512 + h*64 + d] * q2[h*64+d]
  #pragma unroll
  for (int k = 0; k < 12; ++k) {
    const int e = tid + k * 256;        // 0..3071
    const int h = e / DINO_;
    const int j = e % DINO_;
    const float* wrow = Wk + j * CLIP_ + h * D_;
    const float* qrow = q2 + h * D_;
    float acc = 0.0f;
    #pragma unroll 8
    for (int d = 0; d < D_; ++d) acc += wrow[d] * qrow[d];
    qk[(b * H_ + h) * DINO_ + j] = acc * rs;
  }
}

// ---------------------------------------------------------------------------
// Kernel C (main): fused logits + online softmax + attn-weighted dino sum.
// grid = B*CHUNKS = 512 blocks, 256 threads (4 waves). Each wave processes
// patches of its chunk strided by 4. dino is read from HBM exactly once.
// Writes per-(b,chunk) partials: s~[8][384] (unnorm. exp-weighted sum),
// m (running max), l (sum of exp).
// ---------------------------------------------------------------------------
__device__ __forceinline__ float wave_sum(float v) {
  v += __shfl_xor(v, 1);
  v += __shfl_xor(v, 2);
  v += __shfl_xor(v, 4);
  v += __shfl_xor(v, 8);
  v += __shfl_xor(v, 16);
  v += __shfl_xor(v, 32);
  return v;
}

__global__ __launch_bounds__(256, 2) void kmain(const float* __restrict__ dino,
                                                const float* __restrict__ qk,
                                                float* __restrict__ ps,
                                                float* __restrict__ pm,
                                                float* __restrict__ pl) {
  const int blk = blockIdx.x;
  const int b = blk >> 2;
  const int c = blk & 3;
  const int n0 = c * CHUNK_SZ;
  const int n1 = min(N_, n0 + CHUNK_SZ);
  const int tid = threadIdx.x;
  const int w = tid >> 6;
  const int lane = tid & 63;

  // qk fragments in registers: qr[h][i] = qk[b][h][lane + 64*i]
  float qr[H_][6];
  const float* qkb = qk + (size_t)b * H_ * DINO_;
  #pragma unroll
  for (int h = 0; h < H_; ++h)
    #pragma unroll
    for (int i = 0; i < 6; ++i)
      qr[h][i] = qkb[h * DINO_ + lane + 64 * i];

  float m[H_], l[H_], s[H_][6];
  #pragma unroll
  for (int h = 0; h < H_; ++h) {
    m[h] = -INFINITY;
    l[h] = 0.0f;
    #pragma unroll
    for (int i = 0; i < 6; ++i) s[h][i] = 0.0f;
  }

  const float* dbase = dino + (size_t)b * N_ * DINO_;

  int n = n0 + w;
  float x[6] = {0.f, 0.f, 0.f, 0.f, 0.f, 0.f};
  if (n < n1) {
    const float* row = dbase + (size_t)n * DINO_;
    #pragma unroll
    for (int i = 0; i < 6; ++i) x[i] = row[lane + 64 * i];
  }
  while (n < n1) {
    const int nn = n + 4;
    float xn[6] = {0.f, 0.f, 0.f, 0.f, 0.f, 0.f};
    if (nn < n1) {
      const float* row = dbase + (size_t)nn * DINO_;
      #pragma unroll
      for (int i = 0; i < 6; ++i) xn[i] = row[lane + 64 * i];
    }
    // 8 logits for patch n (already scaled; softmax-invariant bias dropped)
    float lg[H_];
    #pragma unroll
    for (int h = 0; h < H_; ++h) {
      float p = 0.0f;
      #pragma unroll
      for (int i = 0; i < 6; ++i) p += qr[h][i] * x[i];
      lg[h] = wave_sum(p);   // wave-uniform result
    }
    #pragma unroll
    for (int h = 0; h < H_; ++h) {
      const float v = lg[h];
      if (v > m[h]) {        // wave-uniform branch; rare after warmup
        const float al = __expf(m[h] - v);
        l[h] *= al;
        #pragma unroll
        for (int i = 0; i < 6; ++i) s[h][i] *= al;
        m[h] = v;
      }
      const float p = __expf(v - m[h]);
      l[h] += p;
      #pragma unroll
      for (int i = 0; i < 6; ++i) s[h][i] += p * x[i];
    }
    #pragma unroll
    for (int i = 0; i < 6; ++i) x[i] = xn[i];
    n = nn;
  }

  // ---- merge 4 waves within the block ----
  __shared__ float rsd[4][H_][DINO_];   // 49,152 B
  __shared__ float rm[4][H_], rl[4][H_];
  __shared__ float aw[4][H_];
  #pragma unroll
  for (int h = 0; h < H_; ++h)
    #pragma unroll
    for (int i = 0; i < 6; ++i) rsd[w][h][lane + 64 * i] = s[h][i];
  if (lane == 0) {
    #pragma unroll
    for (int h = 0; h < H_; ++h) { rm[w][h] = m[h]; rl[w][h] = l[h]; }
  }
  __syncthreads();
  if (tid < H_) {
    const int h = tid;
    float M = rm[0][h];
    #pragma unroll
    for (int w2 = 1; w2 < 4; ++w2) M = fmaxf(M, rm[w2][h]);
    float L = 0.0f;
    #pragma unroll
    for (int w2 = 0; w2 < 4; ++w2) {
      const float a = __expf(rm[w2][h] - M);
      aw[w2][h] = a;
      L += a * rl[w2][h];
    }
    pm[(blk)*H_ + h] = M;
    pl[(blk)*H_ + h] = L;
  }
  __syncthreads();
  #pragma unroll
  for (int k = 0; k < 12; ++k) {
    const int e = tid + 256 * k;     // 0..3071
    const int h = e / DINO_;
    const int d = e % DINO_;
    float acc = 0.0f;
    #pragma unroll
    for (int w2 = 0; w2 < 4; ++w2) acc += aw[w2][h] * rsd[w2][h][d];
    ps[(size_t)blk * H_ * DINO_ + e] = acc;
  }
}

// ---------------------------------------------------------------------------
// Kernel F: merge chunk partials -> normalized s[8][384]; project through Wv
// (+bv, since sum(attn)=1); LayerNorm; write out. grid = 128, 256 threads.
// ---------------------------------------------------------------------------
__global__ __launch_bounds__(256) void kf(const float* __restrict__ ps,
                                          const float* __restrict__ pm,
                                          const float* __restrict__ pl,
                                          const float* __restrict__ Wv,
                                          const float* __restrict__ bv,
                                          const float* __restrict__ gamma,
                                          const float* __restrict__ beta,
                                          float* __restrict__ out) {
  const int b = blockIdx.x;
  const int tid = threadIdx.x;
  const int w = tid >> 6;
  const int lane = tid & 63;
  __shared__ float sf[H_ * DINO_];      // merged normalized s
  __shared__ float co[CHUNKS][H_];
  if (tid < H_) {
    const int h = tid;
    float M = -INFINITY;
    #pragma unroll
    for (int cc = 0; cc < CHUNKS; ++cc)
      M = fmaxf(M, pm[(b * CHUNKS + cc) * H_ + h]);
    float a[CHUNKS];
    float L = 0.0f;
    #pragma unroll
    for (int cc = 0; cc < CHUNKS; ++cc) {
      a[cc] = __expf(pm[(b * CHUNKS + cc) * H_ + h] - M);
      L += a[cc] * pl[(b * CHUNKS + cc) * H_ + h];
    }
    const float rL = 1.0f / L;
    #pragma unroll
    for (int cc = 0; cc < CHUNKS; ++cc) co[cc][h] = a[cc] * rL;
  }
  __syncthreads();
  #pragma unroll
  for (int k = 0; k < 12; ++k) {
    const int e = tid + 256 * k;
    const int h = e / DINO_;
    float acc = 0.0f;
    #pragma unroll
    for (int cc = 0; cc < CHUNKS; ++cc)
      acc += co[cc][h] * ps[((size_t)(b * CHUNKS + cc) * H_) * DINO_ + e];
    sf[e] = acc;
  }
  __syncthreads();
  // projection: out[b][c512] = bv + sum_d sf[h][d] * Wv[d*512 + c512]
  float o[2];
  #pragma unroll
  for (int r = 0; r < 2; ++r) {
    const int cc = tid + r * 256;
    const int h = cc >> 6;
    float acc = bv[cc];
    const float* sh = sf + h * DINO_;
    #pragma unroll 8
    for (int d = 0; d < DINO_; ++d) acc += sh[d] * Wv[d * CLIP_ + cc];
    o[r] = acc;
  }
  // LayerNorm over the 512 outputs of row b
  float sum = o[0] + o[1];
  float sq = o[0] * o[0] + o[1] * o[1];
  sum = wave_sum(sum);
  sq = wave_sum(sq);
  __shared__ float redS[4], redQ[4];
  if (lane == 0) { redS[w] = sum; redQ[w] = sq; }
  __syncthreads();
  float tot = redS[0] + redS[1] + redS[2] + redS[3];
  float totq = redQ[0] + redQ[1] + redQ[2] + redQ[3];
  const float mu = tot * (1.0f / 512.0f);
  const float var = totq * (1.0f / 512.0f) - mu * mu;
  const float rstd = rsqrtf(var + 1e-5f);
  #pragma unroll
  for (int r = 0; r < 2; ++r) {
    const int cc = tid + r * 256;
    out[(size_t)b * CLIP_ + cc] = (o[r] - mu) * rstd * gamma[cc] + beta[cc];
  }
}

// ---------------------------------------------------------------------------
extern "C" void kernel_launch(void* const* d_in, const int* in_sizes, int n_in,
                              void* d_out, int out_size, void* d_ws, size_t ws_size,
                              hipStream_t stream) {
  const float* dino  = (const float*)d_in[0];
  const float* clip  = (const float*)d_in[1];
  const float* Wq    = (const float*)d_in[2];
  const float* bq    = (const float*)d_in[3];
  const float* Wk    = (const float*)d_in[4];
  // d_in[5] = bk: softmax-shift-invariant, dropped
  const float* Wv    = (const float*)d_in[6];
  const float* bv    = (const float*)d_in[7];
  const float* temp  = (const float*)d_in[8];
  const float* gamma = (const float*)d_in[9];
  const float* beta  = (const float*)d_in[10];
  float* out = (float*)d_out;

  float* ws = (float*)d_ws;
  float* qk = ws;                                   // 128*8*384   = 393,216 f
  float* ps = qk + (size_t)B_ * H_ * DINO_;         // 128*4*8*384 = 1,572,864 f
  float* pm = ps + (size_t)B_ * CHUNKS * H_ * DINO_; // 4096 f
  float* pl = pm + (size_t)B_ * CHUNKS * H_;        // 4096 f
  // total ~7.9 MB of workspace

  kab<<<B_, 256, 0, stream>>>(clip, Wq, bq, Wk, temp, qk);
  kmain<<<B_ * CHUNKS, 256, 0, stream>>>(dino, qk, ps, pm, pl);
  kf<<<B_, 256, 0, stream>>>(ps, pm, pl, Wv, bv, gamma, beta, out);
}

// Round 3
// 470.292 us; speedup vs baseline: 1.2418x; 1.2418x over previous
//
#include <hip/hip_runtime.h>
#include <math.h>

#define B_    128
#define N_    1369
#define DINO_ 384
#define CLIP_ 512
#define H_    8
#define CHUNKS 6
#define CH     229   // ceil(1369/6); last chunk = 224

// ---------------------------------------------------------------------------
// helpers
// ---------------------------------------------------------------------------
__device__ __forceinline__ float wave_sum(float v) {
  v += __shfl_xor(v, 1);  v += __shfl_xor(v, 2);  v += __shfl_xor(v, 4);
  v += __shfl_xor(v, 8);  v += __shfl_xor(v, 16); v += __shfl_xor(v, 32);
  return v;
}

// Reduce 8 per-lane head-partials over 64 lanes with 17 shuffles.
// Returns the full sum for head phi(lane) = bit5<<2 | bit4<<1 | bit3.
__device__ __forceinline__ float fold8(const float* v, int lane) {
  float a0, a1, a2, a3;
  {
    float t0 = __shfl_xor(v[0], 32), t1 = __shfl_xor(v[1], 32);
    float t2 = __shfl_xor(v[2], 32), t3 = __shfl_xor(v[3], 32);
    float u0 = __shfl_xor(v[4], 32), u1 = __shfl_xor(v[5], 32);
    float u2 = __shfl_xor(v[6], 32), u3 = __shfl_xor(v[7], 32);
    const bool hi = (lane & 32) != 0;
    a0 = hi ? v[4] + u0 : v[0] + t0;
    a1 = hi ? v[5] + u1 : v[1] + t1;
    a2 = hi ? v[6] + u2 : v[2] + t2;
    a3 = hi ? v[7] + u3 : v[3] + t3;
  }
  float b0, b1;
  {
    float t0 = __shfl_xor(a0, 16), t1 = __shfl_xor(a1, 16);
    float t2 = __shfl_xor(a2, 16), t3 = __shfl_xor(a3, 16);
    const bool hi = (lane & 16) != 0;
    b0 = hi ? a2 + t2 : a0 + t0;
    b1 = hi ? a3 + t3 : a1 + t1;
  }
  float c0;
  {
    float t0 = __shfl_xor(b0, 8), t1 = __shfl_xor(b1, 8);
    const bool hi = (lane & 8) != 0;
    c0 = hi ? b1 + t1 : b0 + t0;
  }
  c0 += __shfl_xor(c0, 4);
  c0 += __shfl_xor(c0, 2);
  c0 += __shfl_xor(c0, 1);
  return c0;
}

// Broadcast: every lane gets all 8 values; P[j] = value of head phi(lane)^j.
__device__ __forceinline__ void bcast8(float p, float* P) {
  P[0] = p;
  P[1] = __shfl_xor(P[0], 8);
  P[2] = __shfl_xor(P[0], 16);
  P[3] = __shfl_xor(P[1], 16);
  P[4] = __shfl_xor(P[0], 32);
  P[5] = __shfl_xor(P[1], 32);
  P[6] = __shfl_xor(P[2], 32);
  P[7] = __shfl_xor(P[3], 32);
}

// ---------------------------------------------------------------------------
// kq: Q[b,c] = bq[c] + clip[b,:]·Wq[:,c].  grid (128,2) x 256.
// ---------------------------------------------------------------------------
__global__ __launch_bounds__(256) void kq(const float* __restrict__ clip,
                                          const float* __restrict__ Wq,
                                          const float* __restrict__ bq,
                                          float* __restrict__ Q) {
  const int b = blockIdx.x;
  const int c = blockIdx.y * 256 + threadIdx.x;
  __shared__ float cl[CLIP_];
  cl[threadIdx.x] = clip[b * CLIP_ + threadIdx.x];
  cl[threadIdx.x + 256] = clip[b * CLIP_ + threadIdx.x + 256];
  __syncthreads();
  float acc = bq[c];
  #pragma unroll 8
  for (int j = 0; j < CLIP_; ++j) acc += cl[j] * Wq[j * CLIP_ + c];
  Q[b * CLIP_ + c] = acc;
}

// ---------------------------------------------------------------------------
// kt: WkT[c][j] = Wk[j][c]   (384x512 -> 512x384).  grid (8,6) x 256.
// ---------------------------------------------------------------------------
__global__ __launch_bounds__(256) void kt(const float* __restrict__ Wk,
                                          float* __restrict__ WkT) {
  __shared__ float tile[64][65];
  const int tx = threadIdx.x & 63, ty = threadIdx.x >> 6;
  const int c0 = blockIdx.x * 64, j0 = blockIdx.y * 64;
  #pragma unroll
  for (int k = 0; k < 16; ++k) {
    const int jj = ty + 4 * k;
    tile[jj][tx] = Wk[(j0 + jj) * CLIP_ + c0 + tx];
  }
  __syncthreads();
  #pragma unroll
  for (int k = 0; k < 16; ++k) {
    const int cc = ty + 4 * k;
    WkT[(size_t)(c0 + cc) * DINO_ + j0 + tx] = tile[tx][cc];
  }
}

// ---------------------------------------------------------------------------
// kqk: qk[b, h*384+j] = rs * sum_d WkT[h*64+d][j] * Q[b, h*64+d].
// grid (128,12) x 256.
// ---------------------------------------------------------------------------
__global__ __launch_bounds__(256) void kqk(const float* __restrict__ WkT,
                                           const float* __restrict__ Q,
                                           const float* __restrict__ temp,
                                           float* __restrict__ qkout) {
  const int b = blockIdx.x;
  const int e = blockIdx.y * 256 + threadIdx.x;   // 0..3071
  __shared__ float qs[CLIP_];
  qs[threadIdx.x] = Q[b * CLIP_ + threadIdx.x];
  qs[threadIdx.x + 256] = Q[b * CLIP_ + threadIdx.x + 256];
  __syncthreads();
  const int h = e / DINO_;
  const int j = e - h * DINO_;
  const float rs = 1.0f / (8.0f * temp[0]);       // scale = sqrt(64)*temperature
  float acc = 0.0f;
  #pragma unroll 8
  for (int d = 0; d < 64; ++d)
    acc += WkT[(size_t)(h * 64 + d) * DINO_ + j] * qs[h * 64 + d];
  qkout[(size_t)b * 3072 + e] = acc * rs;
}

// ---------------------------------------------------------------------------
// kmain: fused logits + (no-max) softmax numerator + attn-weighted dino sum.
// grid 768 x 256 (exactly 3 blocks/CU at launch_bounds(256,3)).
// Per-lane dims: d(i,z) = i*128 + 2*lane + z, i=0..2, z=0..1 (float2 loads).
// Slot j of s[] holds head phi(lane)^j.
// ---------------------------------------------------------------------------
__global__ __launch_bounds__(256, 3) void kmain(const float* __restrict__ dino,
                                                const float* __restrict__ qk,
                                                float* __restrict__ ps,
                                                float* __restrict__ pl) {
  const int blk = blockIdx.x;
  const int b = blk / CHUNKS;
  const int c = blk - b * CHUNKS;
  const int n0 = c * CH;
  const int n1 = min(N_, n0 + CH);
  const int tid = threadIdx.x, w = tid >> 6, lane = tid & 63;
  const int phi = (((lane >> 5) & 1) << 2) | (((lane >> 4) & 1) << 1) | ((lane >> 3) & 1);

  // qk fragments: qr[h][2i+z] = qk[b][h*384 + i*128 + 2*lane + z]
  float qr[H_][6];
  const float* qkb = qk + (size_t)b * 3072;
  #pragma unroll
  for (int h = 0; h < H_; ++h)
    #pragma unroll
    for (int i = 0; i < 3; ++i) {
      const float2 t = *(const float2*)(qkb + h * DINO_ + i * 128 + 2 * lane);
      qr[h][2 * i] = t.x;  qr[h][2 * i + 1] = t.y;
    }

  float s[H_][6];
  float l = 0.0f;
  #pragma unroll
  for (int j = 0; j < H_; ++j)
    #pragma unroll
    for (int k = 0; k < 6; ++k) s[j][k] = 0.0f;

  const float* dbase = dino + (size_t)b * N_ * DINO_;

  for (int n = n0 + w; n < n1; n += 8) {
    const int n2 = n + 4;
    const bool hb = n2 < n1;
    const float* ra = dbase + (size_t)n * DINO_;
    const float* rb = dbase + (size_t)(hb ? n2 : n) * DINO_;
    float2 xa[3], xb[3];
    #pragma unroll
    for (int i = 0; i < 3; ++i) xa[i] = *(const float2*)(ra + i * 128 + 2 * lane);
    #pragma unroll
    for (int i = 0; i < 3; ++i) xb[i] = *(const float2*)(rb + i * 128 + 2 * lane);

    // --- patch A ---
    float va[H_];
    #pragma unroll
    for (int h = 0; h < H_; ++h)
      va[h] = qr[h][0] * xa[0].x + qr[h][1] * xa[0].y + qr[h][2] * xa[1].x
            + qr[h][3] * xa[1].y + qr[h][4] * xa[2].x + qr[h][5] * xa[2].y;
    // --- patch B (interleaves with A's shuffle tree for ILP) ---
    float vb[H_];
    #pragma unroll
    for (int h = 0; h < H_; ++h)
      vb[h] = qr[h][0] * xb[0].x + qr[h][1] * xb[0].y + qr[h][2] * xb[1].x
            + qr[h][3] * xb[1].y + qr[h][4] * xb[2].x + qr[h][5] * xb[2].y;

    const float pa = __expf(fold8(va, lane));
    const float pb = __expf(fold8(vb, lane));
    float Pa[H_], Pb[H_];
    bcast8(pa, Pa);
    bcast8(pb, Pb);

    l += pa;
    #pragma unroll
    for (int j = 0; j < H_; ++j) {
      s[j][0] += Pa[j] * xa[0].x;  s[j][1] += Pa[j] * xa[0].y;
      s[j][2] += Pa[j] * xa[1].x;  s[j][3] += Pa[j] * xa[1].y;
      s[j][4] += Pa[j] * xa[2].x;  s[j][5] += Pa[j] * xa[2].y;
    }
    if (hb) {
      l += pb;
      #pragma unroll
      for (int j = 0; j < H_; ++j) {
        s[j][0] += Pb[j] * xb[0].x;  s[j][1] += Pb[j] * xb[0].y;
        s[j][2] += Pb[j] * xb[1].x;  s[j][3] += Pb[j] * xb[1].y;
        s[j][4] += Pb[j] * xb[2].x;  s[j][5] += Pb[j] * xb[2].y;
      }
    }
  }

  // ---- staged merge of 4 waves (plain sums; no max algebra needed) ----
  __shared__ float sm[2][3072];
  __shared__ float lm[2][H_];
  // addr for slot j, elem k: head = phi^j, word = head*384 + (k>>1)*128 + 2*lane + (k&1)
  if (w >= 2) {
    #pragma unroll
    for (int j = 0; j < H_; ++j)
      #pragma unroll
      for (int k = 0; k < 6; ++k)
        sm[w - 2][(phi ^ j) * DINO_ + (k >> 1) * 128 + 2 * lane + (k & 1)] = s[j][k];
    if ((lane & 7) == 0) lm[w - 2][phi] = l;
  }
  __syncthreads();
  if (w < 2) {
    #pragma unroll
    for (int j = 0; j < H_; ++j)
      #pragma unroll
      for (int k = 0; k < 6; ++k)
        s[j][k] += sm[w][(phi ^ j) * DINO_ + (k >> 1) * 128 + 2 * lane + (k & 1)];
    if ((lane & 7) == 0) l += lm[w][phi];
  }
  __syncthreads();
  if (w == 1) {
    #pragma unroll
    for (int j = 0; j < H_; ++j)
      #pragma unroll
      for (int k = 0; k < 6; ++k)
        sm[0][(phi ^ j) * DINO_ + (k >> 1) * 128 + 2 * lane + (k & 1)] = s[j][k];
    if ((lane & 7) == 0) lm[0][phi] = l;
  }
  __syncthreads();
  if (w == 0) {
    #pragma unroll
    for (int j = 0; j < H_; ++j)
      #pragma unroll
      for (int k = 0; k < 6; ++k)
        s[j][k] += sm[0][(phi ^ j) * DINO_ + (k >> 1) * 128 + 2 * lane + (k & 1)];
    if ((lane & 7) == 0) l += lm[0][phi];
    float* pso = ps + (size_t)blk * 3072;
    #pragma unroll
    for (int j = 0; j < H_; ++j)
      #pragma unroll
      for (int k = 0; k < 6; ++k)
        pso[(phi ^ j) * DINO_ + (k >> 1) * 128 + 2 * lane + (k & 1)] = s[j][k];
    if ((lane & 7) == 0) pl[blk * H_ + phi] = l;
  }
}

// ---------------------------------------------------------------------------
// km: merge chunk partials + normalize by L.  grid 128 x 256.
// sf[b, h*384+d] = (sum_cc ps[b,cc,h*384+d]) / (sum_cc pl[b,cc,h])
// ---------------------------------------------------------------------------
__global__ __launch_bounds__(256) void km(const float* __restrict__ ps,
                                          const float* __restrict__ pl,
                                          float* __restrict__ sf) {
  const int b = blockIdx.x, tid = threadIdx.x;
  __shared__ float rL[H_];
  if (tid < H_) {
    float L = 0.0f;
    #pragma unroll
    for (int cc = 0; cc < CHUNKS; ++cc) L += pl[(b * CHUNKS + cc) * H_ + tid];
    rL[tid] = 1.0f / L;
  }
  __syncthreads();
  #pragma unroll
  for (int r = 0; r < 12; ++r) {
    const int e = tid + 256 * r;
    float acc = 0.0f;
    #pragma unroll
    for (int cc = 0; cc < CHUNKS; ++cc)
      acc += ps[(size_t)(b * CHUNKS + cc) * 3072 + e];
    sf[(size_t)b * 3072 + e] = acc * rL[e / DINO_];
  }
}

// ---------------------------------------------------------------------------
// kf: out[b,c] = LN_c( bv[c] + sum_d sf[b, (c>>6)*384+d] * Wv[d,c] )
// grid 128 x 512.
// ---------------------------------------------------------------------------
__global__ __launch_bounds__(512) void kf(const float* __restrict__ sf,
                                          const float* __restrict__ Wv,
                                          const float* __restrict__ bv,
                                          const float* __restrict__ gamma,
                                          const float* __restrict__ beta,
                                          float* __restrict__ out) {
  const int b = blockIdx.x, tid = threadIdx.x;
  const int w = tid >> 6, lane = tid & 63;
  __shared__ float sfl[3072];
  #pragma unroll
  for (int k = 0; k < 6; ++k) sfl[tid + 512 * k] = sf[(size_t)b * 3072 + tid + 512 * k];
  __syncthreads();
  const float* srow = sfl + (tid >> 6) * DINO_;
  float acc = bv[tid];
  #pragma unroll 8
  for (int d = 0; d < DINO_; ++d) acc += srow[d] * Wv[d * CLIP_ + tid];
  // LayerNorm over 512
  float sum = wave_sum(acc);
  float sq  = wave_sum(acc * acc);
  __shared__ float rS[8], rQ[8];
  if (lane == 0) { rS[w] = sum; rQ[w] = sq; }
  __syncthreads();
  float tot = 0.0f, totq = 0.0f;
  #pragma unroll
  for (int i = 0; i < 8; ++i) { tot += rS[i]; totq += rQ[i]; }
  const float mu = tot * (1.0f / 512.0f);
  const float var = totq * (1.0f / 512.0f) - mu * mu;
  const float rstd = rsqrtf(var + 1e-5f);
  out[(size_t)b * CLIP_ + tid] = (acc - mu) * rstd * gamma[tid] + beta[tid];
}

// ---------------------------------------------------------------------------
extern "C" void kernel_launch(void* const* d_in, const int* in_sizes, int n_in,
                              void* d_out, int out_size, void* d_ws, size_t ws_size,
                              hipStream_t stream) {
  const float* dino  = (const float*)d_in[0];
  const float* clip  = (const float*)d_in[1];
  const float* Wq    = (const float*)d_in[2];
  const float* bq    = (const float*)d_in[3];
  const float* Wk    = (const float*)d_in[4];
  // d_in[5] = bk: softmax shift-invariant, dropped
  const float* Wv    = (const float*)d_in[6];
  const float* bv    = (const float*)d_in[7];
  const float* temp  = (const float*)d_in[8];
  const float* gamma = (const float*)d_in[9];
  const float* beta  = (const float*)d_in[10];
  float* out = (float*)d_out;

  float* ws  = (float*)d_ws;
  float* Q   = ws;                       // 128*512            =    65,536 f
  float* WkT = Q   + 65536;              // 512*384            =   196,608 f
  float* qk  = WkT + 196608;             // 128*3072           =   393,216 f
  float* ps  = qk  + 393216;             // 128*6*3072         = 2,359,296 f
  float* pl  = ps  + 2359296;            // 128*6*8            =     6,144 f
  float* sf  = pl  + 6144;               // 128*3072           =   393,216 f
  // total ~13.7 MB

  kq  <<<dim3(B_, 2),  256, 0, stream>>>(clip, Wq, bq, Q);
  kt  <<<dim3(8, 6),   256, 0, stream>>>(Wk, WkT);
  kqk <<<dim3(B_, 12), 256, 0, stream>>>(WkT, Q, temp, qk);
  kmain<<<B_ * CHUNKS, 256, 0, stream>>>(dino, qk, ps, pl);
  km  <<<B_,           256, 0, stream>>>(ps, pl, sf);
  kf  <<<B_,           512, 0, stream>>>(sf, Wv, bv, gamma, beta, out);
}